// Round 4
// baseline (634.970 us; speedup 1.0000x reference)
//
#include <hip/hip_runtime.h>
#include <hip/hip_bf16.h>
#include <math.h>

typedef __bf16 bf16_t;
typedef _Float16 f16_t;
typedef bf16_t bf16x8 __attribute__((ext_vector_type(8)));
typedef bf16_t bf16x4 __attribute__((ext_vector_type(4)));
typedef f16_t  f16x8  __attribute__((ext_vector_type(8)));
typedef f16_t  f16x4  __attribute__((ext_vector_type(4)));
typedef float  f32x4  __attribute__((ext_vector_type(4)));

// ---------------------------------------------------------------------------
// 4-weight fp32 -> bf16 conversion in one dispatch (blockIdx.y picks weight)
// ---------------------------------------------------------------------------
__global__ __launch_bounds__(256) void cvt_w4(
    const float* __restrict__ w0, const float* __restrict__ w1,
    const float* __restrict__ w2, const float* __restrict__ w3,
    bf16_t* __restrict__ out, int n4) {
  const float* src = blockIdx.y == 0 ? w0 : blockIdx.y == 1 ? w1
                   : blockIdx.y == 2 ? w2 : w3;
  int i = blockIdx.x * 256 + threadIdx.x;
  if (i >= n4) return;
  float4 v = ((const float4*)src)[i];
  bf16x4 o;
  o[0] = (bf16_t)v.x; o[1] = (bf16_t)v.y; o[2] = (bf16_t)v.z; o[3] = (bf16_t)v.w;
  ((bf16x4*)(out + (size_t)blockIdx.y * n4 * 4))[i] = o;
}

// ---------------------------------------------------------------------------
// Row softmax over fp16 logits [nrows x 2048]; overwrites each row in place
// with normalized bf16 P (same 2-byte element pitch, same row addresses).
// ---------------------------------------------------------------------------
__global__ __launch_bounds__(256) void softmax_rows_f16(f16_t* __restrict__ sc) {
  f16_t* rp = sc + (size_t)blockIdx.x * 2048;
  int tid = threadIdx.x;
  f16x8 v = ((const f16x8*)rp)[tid];
  float f[8];
  #pragma unroll
  for (int t = 0; t < 8; t++) f[t] = (float)v[t];

  float m = f[0];
  #pragma unroll
  for (int t = 1; t < 8; t++) m = fmaxf(m, f[t]);
  #pragma unroll
  for (int o = 32; o; o >>= 1) m = fmaxf(m, __shfl_xor(m, o));
  __shared__ float redm[4];
  if ((tid & 63) == 0) redm[tid >> 6] = m;
  __syncthreads();
  m = fmaxf(fmaxf(redm[0], redm[1]), fmaxf(redm[2], redm[3]));

  float s = 0.f;
  #pragma unroll
  for (int t = 0; t < 8; t++) { f[t] = __expf(f[t] - m); s += f[t]; }
  #pragma unroll
  for (int o = 32; o; o >>= 1) s += __shfl_xor(s, o);
  __shared__ float reds[4];
  if ((tid & 63) == 0) reds[tid >> 6] = s;
  __syncthreads();
  s = reds[0] + reds[1] + reds[2] + reds[3];
  float inv = 1.0f / s;

  bf16x8 o8;
  #pragma unroll
  for (int t = 0; t < 8; t++) o8[t] = (bf16_t)(f[t] * inv);
  ((bf16x8*)rp)[tid] = o8;
}

// ---------------------------------------------------------------------------
// epilogue store helpers (full-line coalesced vector stores)
// ---------------------------------------------------------------------------
__device__ __forceinline__ void store4(float* p, float4 v) { *(float4*)p = v; }
__device__ __forceinline__ void store4(bf16_t* p, float4 v) {
  bf16x4 o; o[0] = (bf16_t)v.x; o[1] = (bf16_t)v.y;
  o[2] = (bf16_t)v.z; o[3] = (bf16_t)v.w; *(bf16x4*)p = o;
}
__device__ __forceinline__ void store4(f16_t* p, float4 v) {
  f16x4 o; o[0] = (f16_t)v.x; o[1] = (f16_t)v.y;
  o[2] = (f16_t)v.z; o[3] = (f16_t)v.w; *(f16x4*)p = o;
}

// ---------------------------------------------------------------------------
// 256x256 8-phase bf16 MFMA GEMM, C = scale * (A @ B^T) + bias.
// Core schedule identical to the verified r3 kernel (10-slot 16KB ring,
// full K-tile prefetch lead, counted boundary vmcnt at ph3, pipelined
// ds_reads, setprio around MFMA, st_16x32 swizzle, 0 bank conflicts).
// New template modes:
//  AF32: A source is fp32; A-halves are reg-staged (4 global_load_dwordx4
//    ph1/ph2 -> cvt -> 2 swizzled ds_write_b128 in ph4 under MFMA cover).
//    Per-tile vmem ops become 12 (A 4+4, B 2+2) -> boundary vmcnt(10);
//    prologue vmcnt(4) + lgkmcnt(0) before the publish barrier. In-loop
//    ds_write publication: writes are older (lgkm FIFO) than ph1's 8 reads,
//    which the compiler fully drains before ph1's MFMA -- one barrier before
//    any other wave reads the slot (first read is ph4 of the next tile).
//  TOUT: store C transposed as bf16: element (m,n) -> C[(m>>11)*N*ldc +
//    n*ldc + (m&2047)] -- writes V^T directly, eliminating the transpose
//    kernel. Coalesced 16B spans along m.
// Requires M%256==0, N%256==0, nk>=3, lda/ldb 8-elem aligned.
// ---------------------------------------------------------------------------
#define BM 256
#define BN 256
#define BK 64

__device__ __forceinline__ void load16_lds(const bf16_t* g, bf16_t* l) {
  __builtin_amdgcn_global_load_lds(
      (__attribute__((address_space(1))) void*)const_cast<bf16_t*>(g),
      (__attribute__((address_space(3))) void*)l, 16, 0, 0);
}

template <typename CT, bool AF32, bool TOUT>
__global__ __launch_bounds__(512, 2) void gemm256(
    const void* __restrict__ Av, int lda, size_t strA,
    const bf16_t* __restrict__ B, int ldb, size_t strB,
    CT* __restrict__ C, int ldc, size_t strC,
    const float* __restrict__ bias, float scale,
    int K, int batch_on_x) {
  __shared__ __align__(16) char smem[10][16384];  // 160 KiB ring
  char* smem0 = &smem[0][0];

  int bz, mt, nt;
  if (batch_on_x) { bz = blockIdx.x; nt = blockIdx.y; mt = blockIdx.z; }
  else            { mt = blockIdx.x; nt = blockIdx.y; bz = blockIdx.z; }
  const bf16_t* A16 = (const bf16_t*)Av + (AF32 ? 0 : (size_t)bz * strA);
  const float*  A32 = (const float*)Av + (AF32 ? (size_t)bz * strA : 0);
  B += (size_t)bz * strB;
  C += (size_t)bz * strC;
  int m0 = mt * BM, n0 = nt * BN;
  int tid  = threadIdx.x;
  int lane = tid & 63, wv = tid >> 6;
  int wrow = wv >> 2;        // 0..1  (128 M-rows each)
  int wcol = wv & 3;         // 0..3  (64 N-cols each)

  f32x4 acc[8][4];
  #pragma unroll
  for (int i = 0; i < 8; i++)
    #pragma unroll
    for (int j = 0; j < 4; j++) acc[i][j] = (f32x4)0.f;

  int lrow = lane & 15;
  int lk8  = (lane >> 4) * 8;       // k element offset 0/8/16/24
  int xm   = (lrow & 8) << 2;       // st_16x32 read-side XOR (bit5)

  // swizzled ds_read of one bf16x8 fragment from a 16KB half-slot.
  auto rd = [&](const char* half, int blk, int kcol) -> bf16x8 {
    int byte = (((blk << 1) + (kcol >> 5)) << 10)
             + (lrow << 6) + (((kcol & 31) << 1) ^ xm);
    return *(const bf16x8*)(half + byte);
  };

  // gload-staged half (bf16 source): LDS dest linear, global source
  // inverse-swizzled so swizzled ds_reads see (row, col) correctly.
  auto stage_g = [&](const bf16_t* g, int rb, int ld, int k0, int slot) {
    char* dstb = smem0 + slot * 16384;
    #pragma unroll
    for (int q = 0; q < 2; q++) {
      int l = q * 8192 + wv * 1024 + lane * 16;
      int inner = l & 1023, s = l >> 10;
      int rl   = ((s >> 1) << 4) | (inner >> 6);
      int colb = (inner & 63) ^ (((inner >> 9) & 1) << 5);
      int col  = ((s & 1) << 5) | (colb >> 1);
      load16_lds(g + (size_t)(rb + rl) * ld + k0 + col,
                 (bf16_t*)(dstb + q * 8192 + wv * 1024));
    }
  };

  // AF32: issue the 4 f32 loads for A-half hf of tile th (linear, coalesced)
  auto ldA32 = [&](int th, int hf, f32x4* r) {
    #pragma unroll
    for (int q = 0; q < 2; q++) {
      int sub  = q * 8 + wv;
      int grow = hf * 128 + (sub >> 1) * 16 + (lane >> 2);
      int gcol = (sub & 1) * 32 + (lane & 3) * 8;
      const float* gp = A32 + (size_t)(m0 + grow) * lda + th * BK + gcol;
      r[2 * q]     = *(const f32x4*)gp;
      r[2 * q + 1] = *(const f32x4*)(gp + 4);
    }
  };
  // AF32: cvt + swizzled ds_write of a staged A-half into ring slot.
  auto wrA = [&](const f32x4* r, int slot) {
    char* db = smem0 + slot * 16384;
    #pragma unroll
    for (int q = 0; q < 2; q++) {
      int dl  = q * 8192 + wv * 1024 + lane * 16;
      int dst = dl ^ (((dl >> 9) & 1) << 5);
      bf16x8 o;
      #pragma unroll
      for (int e = 0; e < 4; e++) {
        o[e]     = (bf16_t)r[2 * q][e];
        o[4 + e] = (bf16_t)r[2 * q + 1][e];
      }
      *(bf16x8*)(db + dst) = o;
    }
  };

  int nk = K / BK;
  int bl = (wcol & 1) * 4;          // B block base within its half

  f32x4 rA0[4], rA1[4];             // AF32 in-flight A halves (32 VGPR)

  // ---- prologue: tiles 0,1 into slots 0..7; tile 0 resident at the barrier
  if constexpr (AF32) {
    f32x4 rP[4][4];
    #pragma unroll
    for (int tt = 0; tt < 2; ++tt)
      #pragma unroll
      for (int hf = 0; hf < 2; ++hf)
        if (tt < nk) ldA32(tt, hf, rP[tt * 2 + hf]);
    #pragma unroll
    for (int tt = 0; tt < 2; ++tt)
      #pragma unroll
      for (int hf = 0; hf < 2; ++hf)
        if (tt < nk) stage_g(B, n0 + hf * 128, ldb, tt * BK, tt * 4 + 2 + hf);
    #pragma unroll
    for (int tt = 0; tt < 2; ++tt)
      #pragma unroll
      for (int hf = 0; hf < 2; ++hf)
        if (tt < nk) wrA(rP[tt * 2 + hf], tt * 4 + hf);   // compiler waits regs
    asm volatile("s_waitcnt vmcnt(4)" ::: "memory");       // t0 B resident
    asm volatile("s_waitcnt lgkmcnt(0)" ::: "memory");     // publish A writes
    asm volatile("s_barrier" ::: "memory");
  } else {
    #pragma unroll
    for (int h = 0; h < 8; ++h)
      if (h < 4 * nk) {
        int th = h >> 2, hf = h & 3;
        if (hf < 2) stage_g(A16, m0 + hf * 128, lda, th * BK, h);
        else        stage_g(B, n0 + (hf - 2) * 128, ldb, th * BK, h);
      }
    asm volatile("s_waitcnt vmcnt(8)" ::: "memory");
    asm volatile("s_barrier" ::: "memory");
  }

  bf16x8 a0[4][2], a1[4][2], bb[2][2];
  // pre-read tile 0's a0-3 and b01 (slots: A=wrow, B=2+(wcol>>1))
  {
    const char* Ah0 = smem0 + (0 + wrow) * 16384;
    const char* Bh0 = smem0 + (2 + (wcol >> 1)) * 16384;
    #pragma unroll
    for (int i = 0; i < 4; ++i)
      #pragma unroll
      for (int s = 0; s < 2; ++s)
        a0[i][s] = rd(Ah0, i, s * 32 + lk8);
    #pragma unroll
    for (int j = 0; j < 2; ++j)
      #pragma unroll
      for (int s = 0; s < 2; ++s)
        bb[j][s] = rd(Bh0, bl + j, s * 32 + lk8);
  }

  int rs = 0;    // ring slot of current tile's half 4t (always even)
  int ss = 8;    // next stage slot (tile t+2's A0)

  for (int t = 0; t < nk; ++t) {
    bool do_stage = (t + 2 < nk);
    int s0 = ss;
    int s1 = ss + 1; if (s1 >= 10) s1 -= 10;
    int s2 = ss + 2; if (s2 >= 10) s2 -= 10;
    int s3 = ss + 3; if (s3 >= 10) s3 -= 10;
    int sa  = rs + wrow;
    int sb  = rs + 2 + (wcol >> 1); if (sb  >= 10) sb  -= 10;
    int san = rs + 4 + wrow;        if (san >= 10) san -= 10;
    int sbn = rs + 6 + (wcol >> 1); if (sbn >= 10) sbn -= 10;
    const char* Ah  = smem0 + sa  * 16384;
    const char* Bh  = smem0 + sb  * 16384;
    const char* Ahn = smem0 + san * 16384;
    const char* Bhn = smem0 + sbn * 16384;

    // ---- phase 1: read a4-7; stage/load (t+2).A0; MFMA q00
    #pragma unroll
    for (int i = 0; i < 4; ++i)
      #pragma unroll
      for (int s = 0; s < 2; ++s)
        a1[i][s] = rd(Ah, 4 + i, s * 32 + lk8);
    if (do_stage) {
      if constexpr (AF32) ldA32(t + 2, 0, rA0);
      else                stage_g(A16, m0, lda, (t + 2) * BK, s0);
    }
    asm volatile("s_barrier" ::: "memory");
    __builtin_amdgcn_s_setprio(1);
    #pragma unroll
    for (int i = 0; i < 4; ++i)
      #pragma unroll
      for (int j = 0; j < 2; ++j)
        #pragma unroll
        for (int s = 0; s < 2; ++s)
          acc[i][j] = __builtin_amdgcn_mfma_f32_16x16x32_bf16(
              a0[i][s], bb[j][s], acc[i][j], 0, 0, 0);
    __builtin_amdgcn_s_setprio(0);
    asm volatile("s_barrier" ::: "memory");

    // ---- phase 2: stage/load (t+2).A1; MFMA q10
    if (do_stage) {
      if constexpr (AF32) ldA32(t + 2, 1, rA1);
      else                stage_g(A16, m0 + 128, lda, (t + 2) * BK, s1);
    }
    asm volatile("s_barrier" ::: "memory");
    __builtin_amdgcn_s_setprio(1);
    #pragma unroll
    for (int i = 0; i < 4; ++i)
      #pragma unroll
      for (int j = 0; j < 2; ++j)
        #pragma unroll
        for (int s = 0; s < 2; ++s)
          acc[4 + i][j] = __builtin_amdgcn_mfma_f32_16x16x32_bf16(
              a1[i][s], bb[j][s], acc[4 + i][j], 0, 0, 0);
    __builtin_amdgcn_s_setprio(0);
    asm volatile("s_barrier" ::: "memory");

    // ---- phase 3: read b23; stage (t+2).B0; boundary vmcnt; MFMA q11
    #pragma unroll
    for (int j = 0; j < 2; ++j)
      #pragma unroll
      for (int s = 0; s < 2; ++s)
        bb[j][s] = rd(Bh, bl + 2 + j, s * 32 + lk8);
    if (do_stage) stage_g(B, n0, ldb, (t + 2) * BK, s2);
    if constexpr (AF32) {
      if (t <= nk - 3) asm volatile("s_waitcnt vmcnt(10)" ::: "memory");
      else             asm volatile("s_waitcnt vmcnt(0)" ::: "memory");
    } else {
      if (t <= nk - 3) asm volatile("s_waitcnt vmcnt(6)" ::: "memory");
      else             asm volatile("s_waitcnt vmcnt(0)" ::: "memory");
    }
    asm volatile("s_barrier" ::: "memory");
    __builtin_amdgcn_s_setprio(1);
    #pragma unroll
    for (int i = 0; i < 4; ++i)
      #pragma unroll
      for (int j = 0; j < 2; ++j)
        #pragma unroll
        for (int s = 0; s < 2; ++s)
          acc[4 + i][2 + j] = __builtin_amdgcn_mfma_f32_16x16x32_bf16(
              a1[i][s], bb[j][s], acc[4 + i][2 + j], 0, 0, 0);
    __builtin_amdgcn_s_setprio(0);
    asm volatile("s_barrier" ::: "memory");

    // ---- phase 4: stage (t+2).B1; MFMA q01; AF32 A-writes; next-tile reads
    if (do_stage) stage_g(B, n0 + 128, ldb, (t + 2) * BK, s3);
    asm volatile("s_barrier" ::: "memory");
    __builtin_amdgcn_s_setprio(1);
    #pragma unroll
    for (int i = 0; i < 4; ++i)
      #pragma unroll
      for (int j = 0; j < 2; ++j)
        #pragma unroll
        for (int s = 0; s < 2; ++s)
          acc[i][2 + j] = __builtin_amdgcn_mfma_f32_16x16x32_bf16(
              a0[i][s], bb[j][s], acc[i][2 + j], 0, 0, 0);
    __builtin_amdgcn_s_setprio(0);
    if constexpr (AF32) {
      if (do_stage) { wrA(rA0, s0); wrA(rA1, s1); }
    }
    if (t + 1 < nk) {
      #pragma unroll
      for (int j = 0; j < 2; ++j)
        #pragma unroll
        for (int s = 0; s < 2; ++s)
          bb[j][s] = rd(Bhn, bl + j, s * 32 + lk8);
      #pragma unroll
      for (int i = 0; i < 4; ++i)
        #pragma unroll
        for (int s = 0; s < 2; ++s)
          a0[i][s] = rd(Ahn, i, s * 32 + lk8);
    }
    asm volatile("s_barrier" ::: "memory");

    if (do_stage) { ss += 4; if (ss >= 10) ss -= 10; }
    rs += 4; if (rs >= 10) rs -= 10;
  }

  // ---- epilogue: repack C through LDS in 4 quarters of 64x256 fp32 ----
  // acc mapping [m89]: col = wcol*64 + j*16 + (lane&15),
  //                    row = wrow*128 + i*16 + (lane>>4)*4 + r
  float* Cs = (float*)smem0;         // 64 x 260 fp32 (~66 KB, fits ring)
  #pragma unroll
  for (int q = 0; q < 4; ++q) {
    __syncthreads();
    if (wrow == (q >> 1)) {          // wave-uniform branch
      #pragma unroll
      for (int ii = 0; ii < 4; ++ii) {
        int i = (q & 1) * 4 + ii;
        int lr = ii * 16 + (lane >> 4) * 4;            // row within quarter
        #pragma unroll
        for (int j = 0; j < 4; ++j) {
          int lc = wcol * 64 + j * 16 + (lane & 15);   // col within 256
          #pragma unroll
          for (int r = 0; r < 4; ++r)
            Cs[(lr + r) * 260 + lc] = acc[i][j][r];
        }
      }
    }
    __syncthreads();
    if constexpr (TOUT) {
      // transposed store: element (m, n) -> C[(m>>11)*N*ldc + n*ldc + (m&2047)]
      int n = tid & 255, mh = tid >> 8;
      int mbase = m0 + q * 64 + mh * 32;
      int NN = gridDim.y * BN;
      float bvn = bias ? bias[n0 + n] : 0.f;
      CT* dst = C + (size_t)(mbase >> 11) * (size_t)NN * ldc
                  + (size_t)(n0 + n) * ldc + (mbase & 2047);
      #pragma unroll
      for (int g = 0; g < 4; ++g) {
        bf16x8 o;
        #pragma unroll
        for (int e = 0; e < 8; ++e)
          o[e] = (bf16_t)(Cs[(mh * 32 + g * 8 + e) * 260 + n] * scale + bvn);
        *(bf16x8*)(dst + g * 8) = o;
      }
    } else {
      // linear readback: 64 x 256 fp32 = 4096 float4, 512 thr -> 8 each
      #pragma unroll
      for (int io = 0; io < 8; ++io) {
        int idx = io * 512 + tid;
        int r = idx >> 6, c4 = (idx & 63) * 4;
        float4 v = *(const float4*)&Cs[r * 260 + c4];
        int grow = m0 + q * 64 + r;
        int gcol = n0 + c4;
        float4 bv = bias ? *(const float4*)&bias[gcol] : make_float4(0, 0, 0, 0);
        v.x = v.x * scale + bv.x; v.y = v.y * scale + bv.y;
        v.z = v.z * scale + bv.z; v.w = v.w * scale + bv.w;
        store4(C + (size_t)grow * ldc + gcol, v);
      }
    }
  }
}

// ---------------------------------------------------------------------------
// Host-side launcher.  Workspace: 168 MiB (unchanged layout; IN overlay dead).
//   [W bf16 8MiB][SC 64MiB fp16 logits][Qb 32][Kb 32 (VT after scores)][Xb 32]
// Order: Wcvt; projQ(AF32); projK(AF32); scores; projV(AF32+TOUT -> VT=Kb);
//        softmax; PV; out.  (V-proj moved after scores so VT can reuse Kb.)
// ---------------------------------------------------------------------------
extern "C" void kernel_launch(void* const* d_in, const int* in_sizes, int n_in,
                              void* d_out, int out_size, void* d_ws, size_t ws_size,
                              hipStream_t stream) {
  const float* query = (const float*)d_in[0];
  const float* key_  = (const float*)d_in[1];
  const float* value = (const float*)d_in[2];
  const float* Wq = (const float*)d_in[3];
  const float* bq = (const float*)d_in[4];
  const float* Wk = (const float*)d_in[5];
  const float* bk = (const float*)d_in[6];
  const float* Wv = (const float*)d_in[7];
  const float* bv = (const float*)d_in[8];
  const float* Wo = (const float*)d_in[9];
  const float* bo = (const float*)d_in[10];
  float* out = (float*)d_out;

  const int Bb = 8, S = 2048, D = 1024;
  const int MS = Bb * S;                    // 16384
  const size_t ND = (size_t)MS * D;         // 16.7M elements (32 MiB bf16)
  const size_t WD = (size_t)D * D;          // 1M elements (2 MiB bf16)

  char* ws = (char*)d_ws;
  bf16_t* Wqb = (bf16_t*)ws;                //  8 MiB of weights (contiguous)
  bf16_t* Wkb = Wqb + WD;
  bf16_t* Wvb = Wkb + WD;
  bf16_t* Wob = Wvb + WD;
  f16_t*  SC  = (f16_t*)(Wob + WD);         // 64 MiB: fp16 logits [8][S][S]
  bf16_t* Qb  = (bf16_t*)((char*)SC + (size_t)Bb * S * S * 2);  // 32 MiB
  bf16_t* Kb  = Qb + ND;                    // 32 MiB; VT overlays after scores
  bf16_t* VT  = Kb;
  bf16_t* Xb  = Kb + ND;                    // 32 MiB: attention X
  // total: 168 MiB

  const int n4w = (int)(WD / 4);
  dim3 blk(512);
  dim3 pgrid(MS / BM, D / BN, 1);           // 256 blocks = 1/CU

  // all 4 weight conversions in one dispatch
  cvt_w4<<<dim3(n4w / 256, 4), 256, 0, stream>>>(Wq, Wk, Wv, Wo, Wqb, n4w);

  // Q/K projections straight from fp32 inputs (M=16384, N=K=1024)
  gemm256<bf16_t, true, false><<<pgrid, blk, 0, stream>>>(
      query, D, 0, Wqb, D, 0, Qb, D, 0, bq, 1.f, D, 0);
  gemm256<bf16_t, true, false><<<pgrid, blk, 0, stream>>>(
      key_, D, 0, Wkb, D, 0, Kb, D, 0, bk, 1.f, D, 0);

  // scores = Q @ K^T / sqrt(128) -> fp16 (M=N=2048/batch, K=1024), batch on x
  gemm256<f16_t, false, false><<<dim3(Bb, S / BN, S / BM), blk, 0, stream>>>(
      Qb, D, (size_t)S * D, Kb, D, (size_t)S * D, SC, S, (size_t)S * S,
      nullptr, 0.08838834764831845f, D, 1);

  // V projection straight from fp32, TRANSPOSED output into VT (=Kb, now dead)
  gemm256<bf16_t, true, true><<<pgrid, blk, 0, stream>>>(
      value, D, 0, Wvb, D, 0, VT, S /*ldc = S*/, 0, bv, 1.f, D, 0);

  // softmax all rows -> bf16 P in place (row pitch 2048 elements)
  softmax_rows_f16<<<dim3(Bb * S), 256, 0, stream>>>(SC);

  // X = P @ (V^T)^T (M=2048, N=1024, K=2048 per batch), batch on x
  gemm256<bf16_t, false, false><<<dim3(Bb, D / BN, S / BM), blk, 0, stream>>>(
      (const bf16_t*)SC, S, (size_t)S * S, VT, S, (size_t)D * S,
      Xb, D, (size_t)S * D, nullptr, 1.f, S, 1);

  // out = X @ Wo^T + bo -> fp32 (M=16384, N=K=1024)
  gemm256<float, false, false><<<pgrid, blk, 0, stream>>>(
      Xb, D, 0, Wob, D, 0, out, D, 0, bo, 1.f, D, 0);
}